// Round 1
// baseline (1724.113 us; speedup 1.0000x reference)
//
#include <hip/hip_runtime.h>
#include <math.h>

#define TOK    16384
#define DMODEL 1024
#define H3     3072
#define QKD    2048      // Q|K packed row width
#define LSEQ   8192
#define CHUNK  8192      // tokens per qkv chunk (chunk == batch row)

typedef unsigned short ushort_t;
using bf16x8 = __attribute__((ext_vector_type(8))) __bf16;
using us8    = __attribute__((ext_vector_type(8))) unsigned short;
using f32x4  = __attribute__((ext_vector_type(4))) float;

// ---- bf16 helpers (RNE) ----
__device__ __forceinline__ unsigned short f2bf(float f) {
    unsigned int u = __float_as_uint(f);
    u += 0x7FFF + ((u >> 16) & 1);
    return (unsigned short)(u >> 16);
}
__device__ __forceinline__ float bf2f(unsigned short b) {
    return __uint_as_float(((unsigned int)b) << 16);
}
__device__ __forceinline__ bf16x8 us8_to_bf(us8 u) {
    union { us8 u; bf16x8 b; } t; t.u = u; return t.b;
}

// async global->LDS, 16B per lane, dst = uniform base + lane*16
__device__ __forceinline__ void gld16(const void* g, void* l) {
    __builtin_amdgcn_global_load_lds(
        (const __attribute__((address_space(1))) unsigned int*)g,
        (__attribute__((address_space(3))) unsigned int*)l, 16, 0, 0);
}

// ---------------------------------------------------------------------------
// split fp32 -> (hi, lo) bf16 pair.  n4 = n/4.
// perm!=0: gather x rows parity-major per 8192-chunk:  p = parity*4096+pos,
// orig = pos*2+parity  (makes stride-2 segments contiguous for branch 1).
// ---------------------------------------------------------------------------
__global__ __launch_bounds__(256) void split_f32(
    const float* __restrict__ s, ushort_t* __restrict__ h,
    ushort_t* __restrict__ l, int n4, int perm)
{
    int i = blockIdx.x * 256 + threadIdx.x;
    if (i >= n4) return;
    int src = i;
    if (perm) {
        int row = i >> 8, col = i & 255;              // 1024 floats = 256 float4 per row
        int chunk = row >> 13, p = row & 8191;
        int orow = (chunk << 13) + ((p & 4095) * 2 + (p >> 12));
        src = orow * 256 + col;
    }
    float4 v = ((const float4*)s)[src];
    ushort4 hp, lp;
    hp.x = f2bf(v.x); lp.x = f2bf(v.x - bf2f(hp.x));
    hp.y = f2bf(v.y); lp.y = f2bf(v.y - bf2f(hp.y));
    hp.z = f2bf(v.z); lp.z = f2bf(v.z - bf2f(hp.z));
    hp.w = f2bf(v.w); lp.w = f2bf(v.w - bf2f(hp.w));
    ((ushort4*)h)[i] = hp;
    ((ushort4*)l)[i] = lp;
}

// ---------------------------------------------------------------------------
// Split-bf16 MFMA GEMM (NT), FUSED 3-term K-loop:
//   acc = (Ah+Al)@(Wh+Wl)^T (dropping Al*Wl), then epilogue by mode:
//   mode 0: C = beta*C + scale*(acc+bias)            (fp32, out-proj)
//   mode 1: qkv path: cols<2048 -> split hi/lo [token][2048];
//           cols>=2048 -> split hi/lo TRANSPOSED V^T [hd][M]  (PV B-operand)
// 128x128 tile, BK=32, 256 thr = 4 waves, 16x16x32 MFMA, 4x4 frag-tiles/wave.
// LDS in FRAGMENT layout (lane*16B) -> gld16 order == ds_read_b128 order.
// ---------------------------------------------------------------------------
__global__ __launch_bounds__(256) void gemm_split_nt(
    const ushort_t* __restrict__ Ah, const ushort_t* __restrict__ Al,
    const ushort_t* __restrict__ Wh, const ushort_t* __restrict__ Wl,
    const float* __restrict__ bias, float* __restrict__ C,
    ushort_t* __restrict__ Ch, ushort_t* __restrict__ Cl,
    ushort_t* __restrict__ Vth, ushort_t* __restrict__ Vtl,
    int M, int N, int K, float scale, int beta, int qkv_mode)
{
    __shared__ __align__(16) ushort_t As[2][8 * 512];   // [hi/lo][frag*512]
    __shared__ __align__(16) ushort_t Bs[2][8 * 512];

    const int tid  = threadIdx.x;
    const int lane = tid & 63;
    const int w    = tid >> 6;
    const int m0 = blockIdx.y * 128;
    const int n0 = blockIdx.x * 128;

    // ---- staging: waves 0,1 -> A frags 0-3/4-7 (hi+lo); waves 2,3 -> B ----
    const bool isA = (w < 2);
    const int  fb  = (w & 1) * 4;
    const int  blk0 = isA ? m0 : n0;
    long soff[4];
#pragma unroll
    for (int i = 0; i < 4; ++i) {
        int row = blk0 + (fb + i) * 16 + (lane & 15);
        soff[i] = (long)row * K + (lane >> 4) * 8;
    }
    ushort_t* dst_h = (isA ? As[0] : Bs[0]) + fb * 512;
    ushort_t* dst_l = (isA ? As[1] : Bs[1]) + fb * 512;
    const ushort_t* src_h = isA ? Ah : Wh;
    const ushort_t* src_l = isA ? Al : Wl;

    // ---- compute: wave -> 64x64 quadrant, 4x4 frags ----
    const int am0 = (w >> 1) * 4;
    const int bn0 = (w & 1) * 4;

    f32x4 acc[4][4];
#pragma unroll
    for (int i = 0; i < 4; ++i)
#pragma unroll
        for (int j = 0; j < 4; ++j) acc[i][j] = (f32x4){0.f, 0.f, 0.f, 0.f};

    for (int k0 = 0; k0 < K; k0 += 32) {
#pragma unroll
        for (int i = 0; i < 4; ++i) {
            gld16(src_h + soff[i] + k0, dst_h + i * 512);
            gld16(src_l + soff[i] + k0, dst_l + i * 512);
        }
        __syncthreads();

        bf16x8 ah[4], al[4], bh[4], bl[4];
#pragma unroll
        for (int i = 0; i < 4; ++i) {
            ah[i] = *(const bf16x8*)(As[0] + (am0 + i) * 512 + lane * 8);
            al[i] = *(const bf16x8*)(As[1] + (am0 + i) * 512 + lane * 8);
            bh[i] = *(const bf16x8*)(Bs[0] + (bn0 + i) * 512 + lane * 8);
            bl[i] = *(const bf16x8*)(Bs[1] + (bn0 + i) * 512 + lane * 8);
        }
#pragma unroll
        for (int i = 0; i < 4; ++i)
#pragma unroll
            for (int j = 0; j < 4; ++j)
                acc[i][j] = __builtin_amdgcn_mfma_f32_16x16x32_bf16(
                    ah[i], bh[j], acc[i][j], 0, 0, 0);
#pragma unroll
        for (int i = 0; i < 4; ++i)
#pragma unroll
            for (int j = 0; j < 4; ++j)
                acc[i][j] = __builtin_amdgcn_mfma_f32_16x16x32_bf16(
                    al[i], bh[j], acc[i][j], 0, 0, 0);
#pragma unroll
        for (int i = 0; i < 4; ++i)
#pragma unroll
            for (int j = 0; j < 4; ++j)
                acc[i][j] = __builtin_amdgcn_mfma_f32_16x16x32_bf16(
                    ah[i], bl[j], acc[i][j], 0, 0, 0);
        __syncthreads();
    }

    // ---- epilogue: D row=(lane>>4)*4+reg, col=lane&15 ----
    const int wm = (w >> 1) * 64, wn = (w & 1) * 64;
    const int r0 = (lane >> 4) * 4;
    const int cn = lane & 15;

    if (qkv_mode) {
        const bool isV = (n0 >= 1024 * 2);
#pragma unroll
        for (int j = 0; j < 4; ++j) {
            int col = n0 + wn + j * 16 + cn;
            float bv = bias[col];
#pragma unroll
            for (int i = 0; i < 4; ++i) {
                int rowb = m0 + wm + i * 16 + r0;
                if (isV) {
                    unsigned short ha[4], la[4];
#pragma unroll
                    for (int r = 0; r < 4; ++r) {
                        float v = acc[i][j][r] + bv;
                        ha[r] = f2bf(v);
                        la[r] = f2bf(v - bf2f(ha[r]));
                    }
                    size_t vidx = (size_t)(col - 2048) * M + rowb;
                    *(ushort4*)(Vth + vidx) = make_ushort4(ha[0], ha[1], ha[2], ha[3]);
                    *(ushort4*)(Vtl + vidx) = make_ushort4(la[0], la[1], la[2], la[3]);
                } else {
#pragma unroll
                    for (int r = 0; r < 4; ++r) {
                        float v = acc[i][j][r] + bv;
                        unsigned short hb = f2bf(v);
                        size_t idx = (size_t)(rowb + r) * QKD + col;
                        Ch[idx] = hb;
                        Cl[idx] = f2bf(v - bf2f(hb));
                    }
                }
            }
        }
    } else {
#pragma unroll
        for (int j = 0; j < 4; ++j) {
            int col = n0 + wn + j * 16 + cn;
            float bv = bias[col];
#pragma unroll
            for (int i = 0; i < 4; ++i) {
                int rowb = m0 + wm + i * 16 + r0;
#pragma unroll
                for (int r = 0; r < 4; ++r) {
                    size_t idx = (size_t)(rowb + r) * N + col;
                    float v = scale * (acc[i][j][r] + bv);
                    C[idx] = beta ? (C[idx] + v) : v;
                }
            }
        }
    }
}

// ---------------------------------------------------------------------------
// MFMA flash attention over contiguous 512-token segments (both branches:
// branch 1's x was pre-permuted parity-major so its segments are contiguous).
// Block = (64-row Q tile qt, head h, segment z); 256 thr = 4 waves.
// Wave w: Q rows w*16..w*16+15.  Split-bf16 3-term QK^T and PV.
// K frags + V^T frags staged to LDS in fragment layout via gld16 (conflict-
// free lane*16B).  P goes through a padded per-wave LDS tile to reach the
// A-fragment layout.  Output scattered to original token order when perm=1.
// ---------------------------------------------------------------------------
__global__ __launch_bounds__(256) void attn_mfma(
    const ushort_t* __restrict__ qkh, const ushort_t* __restrict__ qkl,
    const ushort_t* __restrict__ vth, const ushort_t* __restrict__ vtl,
    ushort_t* __restrict__ aoh, ushort_t* __restrict__ aol,
    int perm, long tok0)
{
    __shared__ __align__(16) ushort_t Kls[2][4096];   // [hi/lo][(j*2+ks)*512+lane*8]
    __shared__ __align__(16) ushort_t Vls[2][4096];   // V^T frags, same layout
    __shared__ __align__(16) float    Ps[4][16 * 68]; // per-wave P / O transpose pad

    const int tid  = threadIdx.x;
    const int lane = tid & 63;
    const int w    = tid >> 6;
    const int l15  = lane & 15;
    const int lg   = lane >> 4;
    const int qt = blockIdx.x, h = blockIdx.y, z = blockIdx.z;
    const int base = z * 512;

    // ---- Q fragments in registers: lane holds Q[row=l15][k=32*ks+lg*8+e] ----
    bf16x8 qh[2], ql[2];
    {
        const int qrow = base + qt * 64 + w * 16 + l15;
        const size_t rb = (size_t)qrow * QKD + h * 64 + lg * 8;
        qh[0] = *(const bf16x8*)(qkh + rb);
        ql[0] = *(const bf16x8*)(qkl + rb);
        qh[1] = *(const bf16x8*)(qkh + rb + 32);
        ql[1] = *(const bf16x8*)(qkl + rb + 32);
    }

    // ---- staging: waves 0,1 -> K frags {0,1}/{2,3}; waves 2,3 -> V^T ----
    const bool isV = (w >> 1) != 0;
    const int  jm  = (w & 1) * 2;
    const ushort_t* srcH = isV ? vth : qkh;
    const ushort_t* srcL = isV ? vtl : qkl;
    size_t so[4];
    ushort_t *dH[4], *dL[4];
#pragma unroll
    for (int dj = 0; dj < 2; ++dj)
#pragma unroll
        for (int ks = 0; ks < 2; ++ks) {
            const int j = jm + dj, idx = dj * 2 + ks;
            if (!isV)   // K[key=base+16j+l15][d=32ks+lg*8..], keys row-major
                so[idx] = (size_t)(base + 16 * j + l15) * QKD + 1024 + h * 64 + 32 * ks + lg * 8;
            else        // V^T[d=h*64+16j+l15][tok=base+32ks+lg*8..], tokens contiguous
                so[idx] = (size_t)(h * 64 + 16 * j + l15) * CHUNK + base + 32 * ks + lg * 8;
            dH[idx] = (isV ? Vls[0] : Kls[0]) + (j * 2 + ks) * 512;
            dL[idx] = (isV ? Vls[1] : Kls[1]) + (j * 2 + ks) * 512;
        }
    const size_t kstep = isV ? 64 : (size_t)64 * QKD;

    f32x4 oacc[4];
#pragma unroll
    for (int j = 0; j < 4; ++j) oacc[j] = (f32x4){0.f, 0.f, 0.f, 0.f};
    float m_r[4] = {-INFINITY, -INFINITY, -INFINITY, -INFINITY};
    float l_r[4] = {0.f, 0.f, 0.f, 0.f};
    float* const pw = Ps[w];

    for (int kt = 0; kt < 8; ++kt) {
#pragma unroll
        for (int i = 0; i < 4; ++i) {
            gld16(srcH + so[i], dH[i]);
            gld16(srcL + so[i], dL[i]);
            so[i] += kstep;
        }
        __syncthreads();   // drains vmcnt: gld16 tiles complete

        // ---- S = Q K^T, 3-term split; lane: rows lg*4+r, col 16j+l15 ----
        f32x4 s[4];
#pragma unroll
        for (int j = 0; j < 4; ++j) s[j] = (f32x4){0.f, 0.f, 0.f, 0.f};
#pragma unroll
        for (int j = 0; j < 4; ++j)
#pragma unroll
            for (int ks = 0; ks < 2; ++ks) {
                const bf16x8 kh = *(const bf16x8*)(&Kls[0][(j * 2 + ks) * 512 + lane * 8]);
                const bf16x8 kl = *(const bf16x8*)(&Kls[1][(j * 2 + ks) * 512 + lane * 8]);
                s[j] = __builtin_amdgcn_mfma_f32_16x16x32_bf16(qh[ks], kh, s[j], 0, 0, 0);
                s[j] = __builtin_amdgcn_mfma_f32_16x16x32_bf16(ql[ks], kh, s[j], 0, 0, 0);
                s[j] = __builtin_amdgcn_mfma_f32_16x16x32_bf16(qh[ks], kl, s[j], 0, 0, 0);
            }

        // ---- wave-parallel online softmax (reduce across 16 lanes/group) ----
        float alpha[4];
#pragma unroll
        for (int r = 0; r < 4; ++r) {
            float v = fmaxf(fmaxf(s[0][r], s[1][r]), fmaxf(s[2][r], s[3][r]));
            v = fmaxf(v, __shfl_xor(v, 1));
            v = fmaxf(v, __shfl_xor(v, 2));
            v = fmaxf(v, __shfl_xor(v, 4));
            v = fmaxf(v, __shfl_xor(v, 8));
            const float mn = fmaxf(m_r[r], 0.125f * v);
            alpha[r] = __expf(m_r[r] - mn);
            m_r[r] = mn;
            float sum = 0.f;
#pragma unroll
            for (int j = 0; j < 4; ++j) {
                const float p = __expf(fmaf(0.125f, s[j][r], -mn));
                s[j][r] = p;
                sum += p;
            }
            sum += __shfl_xor(sum, 1);
            sum += __shfl_xor(sum, 2);
            sum += __shfl_xor(sum, 4);
            sum += __shfl_xor(sum, 8);
            l_r[r] = l_r[r] * alpha[r] + sum;
        }

        // ---- P -> per-wave LDS [16][68] (pad kills bank conflicts) ----
#pragma unroll
        for (int r = 0; r < 4; ++r)
#pragma unroll
            for (int j = 0; j < 4; ++j)
                pw[(lg * 4 + r) * 68 + 16 * j + l15] = s[j][r];
        asm volatile("s_waitcnt lgkmcnt(0)" ::: "memory");
        __builtin_amdgcn_sched_barrier(0);   // cross-lane RAW inside the wave

        // rescale O by alpha (row = lg*4+r)
#pragma unroll
        for (int j = 0; j < 4; ++j)
#pragma unroll
            for (int r = 0; r < 4; ++r) oacc[j][r] *= alpha[r];

        // ---- O += P V  (P as A-frag: lane row=l15, k=32ks+lg*8+e) ----
#pragma unroll
        for (int ks = 0; ks < 2; ++ks) {
            const float* pp = pw + l15 * 68 + ks * 32 + lg * 8;
            const float4 pa = *(const float4*)pp;
            const float4 pb = *(const float4*)(pp + 4);
            const float pf[8] = {pa.x, pa.y, pa.z, pa.w, pb.x, pb.y, pb.z, pb.w};
            us8 hu, lu;
#pragma unroll
            for (int e = 0; e < 8; ++e) {
                const unsigned short hb = f2bf(pf[e]);
                hu[e] = hb;
                lu[e] = f2bf(pf[e] - bf2f(hb));
            }
            const bf16x8 ph = us8_to_bf(hu);
            const bf16x8 pl = us8_to_bf(lu);
#pragma unroll
            for (int j = 0; j < 4; ++j) {
                const bf16x8 vh = *(const bf16x8*)(&Vls[0][(j * 2 + ks) * 512 + lane * 8]);
                const bf16x8 vl = *(const bf16x8*)(&Vls[1][(j * 2 + ks) * 512 + lane * 8]);
                oacc[j] = __builtin_amdgcn_mfma_f32_16x16x32_bf16(ph, vh, oacc[j], 0, 0, 0);
                oacc[j] = __builtin_amdgcn_mfma_f32_16x16x32_bf16(pl, vh, oacc[j], 0, 0, 0);
                oacc[j] = __builtin_amdgcn_mfma_f32_16x16x32_bf16(ph, vl, oacc[j], 0, 0, 0);
            }
        }
        __syncthreads();   // K/V tiles free for next kt staging
    }

    // ---- epilogue: normalize, LDS transpose, split-bf16 write ----
    float linv[4];
#pragma unroll
    for (int r = 0; r < 4; ++r) linv[r] = 1.f / l_r[r];
#pragma unroll
    for (int j = 0; j < 4; ++j)
#pragma unroll
        for (int r = 0; r < 4; ++r)
            pw[(lg * 4 + r) * 68 + 16 * j + l15] = oacc[j][r] * linv[r];
    asm volatile("s_waitcnt lgkmcnt(0)" ::: "memory");
    __builtin_amdgcn_sched_barrier(0);

    {
        const int rr = lane >> 2, c0 = (lane & 3) * 16;
        const float* rp = pw + rr * 68 + c0;
        const int p_local = base + qt * 64 + w * 16 + rr;
        const long tok = tok0 + (perm ? (long)((p_local & 4095) * 2 + (p_local >> 12))
                                      : (long)p_local);
        const size_t off = (size_t)tok * DMODEL + h * 64 + c0;
        const float4 f0 = *(const float4*)rp;
        const float4 f1 = *(const float4*)(rp + 4);
        const float4 f2 = *(const float4*)(rp + 8);
        const float4 f3 = *(const float4*)(rp + 12);
        const float ff[16] = {f0.x, f0.y, f0.z, f0.w, f1.x, f1.y, f1.z, f1.w,
                              f2.x, f2.y, f2.z, f2.w, f3.x, f3.y, f3.z, f3.w};
        us8 h0, h1, l0, l1;
#pragma unroll
        for (int e = 0; e < 8; ++e) {
            unsigned short hb = f2bf(ff[e]);
            h0[e] = hb; l0[e] = f2bf(ff[e] - bf2f(hb));
            hb = f2bf(ff[e + 8]);
            h1[e] = hb; l1[e] = f2bf(ff[e + 8] - bf2f(hb));
        }
        *(us8*)(aoh + off)     = h0;
        *(us8*)(aoh + off + 8) = h1;
        *(us8*)(aol + off)     = l0;
        *(us8*)(aol + off + 8) = l1;
    }
}

// ---------------------------------------------------------------------------
// out = (attn_br0(x) + attn_br1(x)) / 3.
// br1: x permuted parity-major per chunk -> contiguous segments; attn scatters
// its output back to original token order, so the out-proj GEMM is untouched.
// ws (251.7 MB): xh,xl | wqh,wql | woh,wol | qkh,qkl | vth,vtl | aoh,aol
// ---------------------------------------------------------------------------
extern "C" void kernel_launch(void* const* d_in, const int* in_sizes, int n_in,
                              void* d_out, int out_size, void* d_ws, size_t ws_size,
                              hipStream_t stream) {
    const float* x    = (const float*)d_in[0];
    const float* Wqkv = (const float*)d_in[1];
    const float* bqkv = (const float*)d_in[2];
    const float* Wout = (const float*)d_in[3];
    const float* bout = (const float*)d_in[4];
    float* out = (float*)d_out;

    char* wp = (char*)d_ws;
    ushort_t* xh  = (ushort_t*)wp; wp += (size_t)TOK * DMODEL * 2;
    ushort_t* xl  = (ushort_t*)wp; wp += (size_t)TOK * DMODEL * 2;
    ushort_t* wqh = (ushort_t*)wp; wp += (size_t)H3 * DMODEL * 2;
    ushort_t* wql = (ushort_t*)wp; wp += (size_t)H3 * DMODEL * 2;
    ushort_t* woh = (ushort_t*)wp; wp += (size_t)DMODEL * DMODEL * 2;
    ushort_t* wol = (ushort_t*)wp; wp += (size_t)DMODEL * DMODEL * 2;
    ushort_t* qkh = (ushort_t*)wp; wp += (size_t)CHUNK * QKD * 2;
    ushort_t* qkl = (ushort_t*)wp; wp += (size_t)CHUNK * QKD * 2;
    ushort_t* vth = (ushort_t*)wp; wp += (size_t)DMODEL * CHUNK * 2;
    ushort_t* vtl = (ushort_t*)wp; wp += (size_t)DMODEL * CHUNK * 2;
    ushort_t* aoh = (ushort_t*)wp; wp += (size_t)TOK * DMODEL * 2;
    ushort_t* aol = (ushort_t*)wp;

    dim3 blk(256);
    const float third = 1.0f / 3.0f;

    for (int br = 0; br < 2; ++br) {
        {   // split x (br1: permuted) + this branch's weights
            int n4x = TOK * DMODEL / 4;
            split_f32<<<(n4x + 255) / 256, blk, 0, stream>>>(x, xh, xl, n4x, br);
            int n4q = H3 * DMODEL / 4;
            split_f32<<<(n4q + 255) / 256, blk, 0, stream>>>(
                Wqkv + (size_t)br * H3 * DMODEL, wqh, wql, n4q, 0);
            int n4o = DMODEL * DMODEL / 4;
            split_f32<<<(n4o + 255) / 256, blk, 0, stream>>>(
                Wout + (size_t)br * DMODEL * DMODEL, woh, wol, n4o, 0);
        }
        for (int c = 0; c < TOK / CHUNK; ++c) {
            gemm_split_nt<<<dim3(H3 / 128, CHUNK / 128), blk, 0, stream>>>(
                xh + (size_t)c * CHUNK * DMODEL, xl + (size_t)c * CHUNK * DMODEL,
                wqh, wql, bqkv + (size_t)br * H3, nullptr,
                qkh, qkl, vth, vtl,
                CHUNK, H3, DMODEL, 1.0f, 0, 1);
            attn_mfma<<<dim3(8, 16, 16), blk, 0, stream>>>(
                qkh, qkl, vth, vtl, aoh, aol, br, (long)c * CHUNK);
        }
        gemm_split_nt<<<dim3(DMODEL / 128, TOK / 128), blk, 0, stream>>>(
            aoh, aol, woh, wol, bout + (size_t)br * DMODEL, out,
            nullptr, nullptr, nullptr, nullptr,
            TOK, DMODEL, DMODEL, third, br, 0);
    }
}